// Round 15
// baseline (233.938 us; speedup 1.0000x reference)
//
#include <hip/hip_runtime.h>
#include <hip/hip_bf16.h>
#include <math.h>

#define LATENT 256
#define HIDDEN 512
#define NODE_F 128
#define MAX_NODES 50
#define NPAIRS 1225        // 50*49/2
#define BATCH 128
#define NODE_OUT 6400      // MAX_NODES*NODE_F
#define MTILE 64           // edge rows per tile
#define TPB 10             // tiles per block (20 tiles/batch = 2 blocks/batch)
#define NBLK 256           // edge grid (1 block/CU)

typedef __attribute__((ext_vector_type(8))) short short8;
typedef __attribute__((ext_vector_type(4))) float float4v;

union S8U { short8 s; unsigned int u[4]; };

__device__ __forceinline__ float bf2f(ushort u) {
    union { unsigned int i; float f; } v; v.i = ((unsigned int)u) << 16; return v.f;
}
__device__ __forceinline__ ushort f2bf(float f) {
    union { unsigned int i; float f; } v; v.f = f;
    unsigned int r = v.i + 0x7fffu + ((v.i >> 16) & 1u);   // RNE
    return (ushort)(r >> 16);
}
__device__ __forceinline__ unsigned int pk_bf16(float f0, float f1) {
    __hip_bfloat162 p = __float22bfloat162_rn(float2{f0, f1});   // v_cvt_pk_bf16_f32 (RNE)
    unsigned int w; __builtin_memcpy(&w, &p, 4); return w;
}
__device__ __forceinline__ float sigmoidf(float x) {
    return 1.0f / (1.0f + __expf(-x));
}

// ================= fused prep kernel (R14 verbatim) =================
#define TR3_B0   0
#define EW2_B0   800
#define WIU_B0   832
#define WIV_B0   848
#define ZC_B0    864
#define ND_B0    1120
#define PT_B0    1376
#define PREPK_NB 1381

__global__ __launch_bounds__(256) void k_prep_all(
    const float* __restrict__ nw3, ushort* __restrict__ nw3T,
    const float* __restrict__ ew1, const float* __restrict__ ew2,
    ushort* __restrict__ ew2T, ushort* __restrict__ wijT,
    const float* __restrict__ z, const float* __restrict__ eb1,
    float* __restrict__ Zc,
    const float* __restrict__ nw1, const float* __restrict__ nb1,
    const float* __restrict__ nw2, const float* __restrict__ nb2,
    ushort* __restrict__ h2b, int* __restrict__ ptab)
{
    __shared__ float smem[64 * 65];
    int b = blockIdx.x;
    int tid = threadIdx.x;
    int tx = tid & 63, ty = tid >> 6;   // 64 x 4

    if (b < EW2_B0) {
        int bb = b - TR3_B0;
        int k0 = (bb & 7) * 64;
        int n0 = (bb >> 3) * 64;
#pragma unroll
        for (int r = 0; r < 16; r++) {
            int row = r * 4 + ty;
            smem[row * 65 + tx] = nw3[(k0 + row) * NODE_OUT + n0 + tx];
        }
        __syncthreads();
#pragma unroll
        for (int c = 0; c < 16; c++) {
            int n = c * 4 + ty;
            nw3T[(size_t)(n0 + n) * HIDDEN + k0 + tx] = f2bf(smem[tx * 65 + n]);
        }
    } else if (b < WIU_B0) {
        int bb = b - EW2_B0;
        int k0 = (bb >> 2) * 64;
        int n0 = (bb & 3) * 64;
#pragma unroll
        for (int r = 0; r < 16; r++) {
            int row = r * 4 + ty;
            smem[row * 65 + tx] = ew2[(k0 + row) * 256 + n0 + tx];
        }
        __syncthreads();
#pragma unroll
        for (int c = 0; c < 16; c++) {
            int n = c * 4 + ty;
            ew2T[(n0 + n) * HIDDEN + k0 + tx] = f2bf(smem[tx * 65 + n]);
        }
    } else if (b < WIV_B0) {
        int bb = b - WIU_B0;
        int k0 = (bb >> 3) * 64;
        int n0 = (bb & 7) * 64;
#pragma unroll
        for (int r = 0; r < 16; r++) {
            int row = r * 4 + ty;
            smem[row * 65 + tx] = ew1[(256 + k0 + row) * 512 + n0 + tx];
        }
        __syncthreads();
#pragma unroll
        for (int c = 0; c < 16; c++) {
            int n = c * 4 + ty;
            wijT[(n0 + n) * NODE_F + k0 + tx] = f2bf(smem[tx * 65 + n]);
        }
    } else if (b < ZC_B0) {
        int bb = b - WIV_B0;
        int k0 = (bb >> 3) * 64;
        int n0 = (bb & 7) * 64;
#pragma unroll
        for (int r = 0; r < 16; r++) {
            int row = r * 4 + ty;
            smem[row * 65 + tx] = ew1[(384 + k0 + row) * 512 + n0 + tx];
        }
        __syncthreads();
#pragma unroll
        for (int c = 0; c < 16; c++) {
            int n = c * 4 + ty;
            wijT[(512 + n0 + n) * NODE_F + k0 + tx] = f2bf(smem[tx * 65 + n]);
        }
    } else if (b < ND_B0) {
        int b2 = b - ZC_B0;
        int r = b2 >> 1, o = (b2 & 1) * 256 + tid;
        float* zs = smem;
        zs[tid] = z[r * LATENT + tid];
        __syncthreads();
        float acc = 0.f;
#pragma unroll 8
        for (int k = 0; k < LATENT; k++) acc += zs[k] * ew1[k * HIDDEN + o];
        Zc[r * HIDDEN + o] = acc + eb1[o];
    } else if (b < PT_B0) {
        int b2 = b - ND_B0;
        int r = b2 >> 1, half = b2 & 1;
        float* zs = smem;            // 256 floats
        float* hs = smem + 256;      // 512 floats
        zs[tid] = z[r * LATENT + tid];
        __syncthreads();
        float a0 = 0.f, a1 = 0.f;
#pragma unroll 8
        for (int k = 0; k < LATENT; k++) {
            float zk = zs[k];
            a0 += zk * nw1[k * HIDDEN + tid];
            a1 += zk * nw1[k * HIDDEN + tid + 256];
        }
        hs[tid]       = fmaxf(a0 + nb1[tid], 0.f);
        hs[tid + 256] = fmaxf(a1 + nb1[tid + 256], 0.f);
        __syncthreads();
        int o = half * 256 + tid;
        float acc = 0.f;
#pragma unroll 8
        for (int k = 0; k < HIDDEN; k++) acc += hs[k] * nw2[k * HIDDEN + o];
        acc += nb2[o];
        h2b[r * HIDDEN + o] = f2bf(fmaxf(acc, 0.f));
    } else {
        int p = (b - PT_B0) * 256 + tid;
        if (p < NPAIRS) {
            int i = 0, off = 0;
            while (p - off >= MAX_NODES - 1 - i) { off += MAX_NODES - 1 - i; ++i; }
            int j = i + 1 + (p - off);
            ptab[p] = (i << 8) | j;
        }
    }
}

// ---------------- node layer 3 via MFMA (R14 verbatim)
__global__ __launch_bounds__(256, 4) void k_node_out_mfma(
    const ushort* __restrict__ h2b, const ushort* __restrict__ nw3T,
    const float* __restrict__ nb3, float* __restrict__ node_probs,
    ushort* __restrict__ node_feats)
{
    int tid = threadIdx.x;
    int wave = tid >> 6, lane = tid & 63;
    int m16 = lane & 15, quad = lane >> 4;
    int n0 = (blockIdx.x >> 1) * 64;
    int m0 = (blockIdx.x & 1) * 64;
    int col = n0 + wave * 16 + m16;

    float4v acc[4];
#pragma unroll
    for (int mt = 0; mt < 4; mt++) acc[mt] = (float4v)(0.f);

    const ushort* bb = nw3T + (size_t)col * HIDDEN;
#pragma unroll
    for (int it = 0; it < 16; ++it) {
        int kk = it * 32 + quad * 8;
        short8 b = *(const short8*)(bb + kk);
#pragma unroll
        for (int mt = 0; mt < 4; mt++) {
            short8 a = *(const short8*)(h2b + (m0 + mt * 16 + m16) * HIDDEN + kk);
            acc[mt] = __builtin_amdgcn_mfma_f32_16x16x32_bf16(a, b, acc[mt], 0, 0, 0);
        }
    }
    float bias = nb3[col];
#pragma unroll
    for (int mt = 0; mt < 4; mt++)
#pragma unroll
        for (int t = 0; t < 4; t++) {
            int row = m0 + mt * 16 + quad * 4 + t;
            float v = acc[mt][t] + bias;
            node_probs[(size_t)row * NODE_OUT + col] = sigmoidf(v);
            node_feats[(size_t)row * NODE_OUT + col] = f2bf(v);
        }
}

// ---------------- UV = node_feats @ [W_i|W_j]  (R14 verbatim)
__global__ __launch_bounds__(256, 4) void k_uv(
    const ushort* __restrict__ nf, const ushort* __restrict__ wijT,
    ushort* __restrict__ UV)
{
    int tid = threadIdx.x;
    int wave = tid >> 6, lane = tid & 63;
    int m16 = lane & 15, quad = lane >> 4;
    int bm = blockIdx.x >> 2, bn = blockIdx.x & 3;
    int base = bn * 256 + wave * 64;
    int r0 = bm * 64;

    float4v acc[4][4];
#pragma unroll
    for (int mt = 0; mt < 4; mt++)
#pragma unroll
        for (int nt = 0; nt < 4; nt++) acc[mt][nt] = (float4v)(0.f);

#pragma unroll
    for (int k0 = 0; k0 < NODE_F; k0 += 32) {
        int kk = k0 + quad * 8;
        short8 a0 = *(const short8*)(nf + (r0 + m16) * NODE_F + kk);
        short8 a1 = *(const short8*)(nf + (r0 + 16 + m16) * NODE_F + kk);
        short8 a2 = *(const short8*)(nf + (r0 + 32 + m16) * NODE_F + kk);
        short8 a3 = *(const short8*)(nf + (r0 + 48 + m16) * NODE_F + kk);
#pragma unroll
        for (int nt = 0; nt < 4; nt++) {
            int n = base + nt * 16 + m16;
            short8 b = *(const short8*)(wijT + n * NODE_F + kk);
            acc[0][nt] = __builtin_amdgcn_mfma_f32_16x16x32_bf16(a0, b, acc[0][nt], 0, 0, 0);
            acc[1][nt] = __builtin_amdgcn_mfma_f32_16x16x32_bf16(a1, b, acc[1][nt], 0, 0, 0);
            acc[2][nt] = __builtin_amdgcn_mfma_f32_16x16x32_bf16(a2, b, acc[2][nt], 0, 0, 0);
            acc[3][nt] = __builtin_amdgcn_mfma_f32_16x16x32_bf16(a3, b, acc[3][nt], 0, 0, 0);
        }
    }
#pragma unroll
    for (int nt = 0; nt < 4; nt++) {
        int colg = base + nt * 16 + m16;
#pragma unroll
        for (int mt = 0; mt < 4; mt++)
#pragma unroll
            for (int t = 0; t < 4; t++) {
                int rr = r0 + mt * 16 + quad * 4 + t;
                UV[(size_t)rr * 1024 + colg] = f2bf(acc[mt][nt][t]);
            }
    }
}

// ---------------- fused edge v9: 1024 threads / 16 waves, 4 waves/SIMD.
// Wave covers 16 N-cols (Breg = 64 VGPR); gather split 4 rows/wave.
__global__ __launch_bounds__(1024, 4) void k_edge9(
    const float* __restrict__ Zc, const ushort* __restrict__ UV,
    const ushort* __restrict__ ew2T, const float* __restrict__ ew3,
    const float* __restrict__ eb2, const float* __restrict__ eb3,
    const int* __restrict__ ptab, float* __restrict__ out_edges)
{
    __shared__ __align__(16) ushort h1[2][MTILE][HIDDEN + 8]; // 133,120 B
    __shared__ float part[MTILE][16];                         // 4,096 B
    __shared__ int uo5[TPB][MTILE], vo5[TPB][MTILE];          // 5,120 B

    int tid  = threadIdx.x;
    int blk  = blockIdx.x;
    int b    = blk >> 1;
    int ti0  = (blk & 1) * TPB;

    if (tid < MTILE) {
#pragma unroll
        for (int t = 0; t < TPB; t++) {
            int p = (ti0 + t) * MTILE + tid;
            if (p >= NPAIRS) p = NPAIRS - 1;
            int ij = ptab[p];
            uo5[t][tid] = (b * MAX_NODES + (ij >> 8)) * 1024;
            vo5[t][tid] = (b * MAX_NODES + (ij & 255)) * 1024 + 512;
        }
    }

    int wave = tid >> 6, lane = tid & 63;   // wave 0..15
    int m16 = lane & 15, quad = lane >> 4;
    int c8 = lane * 8;
    int kk0 = quad * 8;

    float4v zA = *(const float4v*)(Zc + b * HIDDEN + c8);
    float4v zB = *(const float4v*)(Zc + b * HIDDEN + c8 + 4);

    // persistent B: wave covers cols [wave*16, wave*16+16)
    const ushort* bb0 = ew2T + (wave * 16 + m16) * HIDDEN;
    short8 Breg[16];
#pragma unroll
    for (int kc = 0; kc < 16; kc++)
        Breg[kc] = *(const short8*)(bb0 + kc * 32 + kk0);
    float eb2v = eb2[wave * 16 + m16];
    float ew3v = ew3[wave * 16 + m16];

    __syncthreads();   // uo5/vo5 ready

    // ---- assemble tile 0: wave handles rows [wave*4, wave*4+4)
#pragma unroll
    for (int rr = 0; rr < 4; rr++) {
        int r = wave * 4 + rr;
        short8 u8 = *(const short8*)(UV + uo5[0][r] + c8);
        short8 v8 = *(const short8*)(UV + vo5[0][r] + c8);
        S8U hh;
#pragma unroll
        for (int e2 = 0; e2 < 4; e2++) {
            float z0 = (e2 < 2) ? zA[e2 * 2] : zB[e2 * 2 - 4];
            float z1 = (e2 < 2) ? zA[e2 * 2 + 1] : zB[e2 * 2 - 3];
            float f0 = fmaxf(z0 + bf2f((ushort)u8[e2 * 2]) + bf2f((ushort)v8[e2 * 2]), 0.f);
            float f1 = fmaxf(z1 + bf2f((ushort)u8[e2 * 2 + 1]) + bf2f((ushort)v8[e2 * 2 + 1]), 0.f);
            hh.u[e2] = pk_bf16(f0, f1);
        }
        *(short8*)&h1[0][r][c8] = hh.s;
    }
    __syncthreads();

    for (int t = 0; t < TPB; t++) {
        int cur = t & 1, nxt = cur ^ 1;
        bool hasNext = (t + 1 < TPB);

        float4v acc2[4];
#pragma unroll
        for (int mt = 0; mt < 4; mt++) acc2[mt] = (float4v)(0.f);

        short8 uu[2], vv[2];
        if (hasNext) {
#pragma unroll
            for (int rr = 0; rr < 2; rr++) {
                int r = wave * 4 + rr;
                uu[rr] = *(const short8*)(UV + uo5[t + 1][r] + c8);
                vv[rr] = *(const short8*)(UV + vo5[t + 1][r] + c8);
            }
        }
#pragma unroll
        for (int it = 0; it < 8; ++it) {
            int kk = it * 32 + kk0;
            short8 a0 = *(const short8*)&h1[cur][m16][kk];
            short8 a1 = *(const short8*)&h1[cur][16 + m16][kk];
            short8 a2 = *(const short8*)&h1[cur][32 + m16][kk];
            short8 a3 = *(const short8*)&h1[cur][48 + m16][kk];
            acc2[0] = __builtin_amdgcn_mfma_f32_16x16x32_bf16(a0, Breg[it], acc2[0], 0, 0, 0);
            acc2[1] = __builtin_amdgcn_mfma_f32_16x16x32_bf16(a1, Breg[it], acc2[1], 0, 0, 0);
            acc2[2] = __builtin_amdgcn_mfma_f32_16x16x32_bf16(a2, Breg[it], acc2[2], 0, 0, 0);
            acc2[3] = __builtin_amdgcn_mfma_f32_16x16x32_bf16(a3, Breg[it], acc2[3], 0, 0, 0);
        }
        if (hasNext) {
#pragma unroll
            for (int rr = 0; rr < 2; rr++) {
                int r = wave * 4 + rr;
                S8U hh;
#pragma unroll
                for (int e2 = 0; e2 < 4; e2++) {
                    float z0 = (e2 < 2) ? zA[e2 * 2] : zB[e2 * 2 - 4];
                    float z1 = (e2 < 2) ? zA[e2 * 2 + 1] : zB[e2 * 2 - 3];
                    float f0 = fmaxf(z0 + bf2f((ushort)uu[rr][e2 * 2]) + bf2f((ushort)vv[rr][e2 * 2]), 0.f);
                    float f1 = fmaxf(z1 + bf2f((ushort)uu[rr][e2 * 2 + 1]) + bf2f((ushort)vv[rr][e2 * 2 + 1]), 0.f);
                    hh.u[e2] = pk_bf16(f0, f1);
                }
                *(short8*)&h1[nxt][r][c8] = hh.s;
            }
#pragma unroll
            for (int rr = 0; rr < 2; rr++) {
                int r = wave * 4 + 2 + rr;
                uu[rr] = *(const short8*)(UV + uo5[t + 1][r] + c8);
                vv[rr] = *(const short8*)(UV + vo5[t + 1][r] + c8);
            }
        }
#pragma unroll
        for (int it = 8; it < 16; ++it) {
            int kk = it * 32 + kk0;
            short8 a0 = *(const short8*)&h1[cur][m16][kk];
            short8 a1 = *(const short8*)&h1[cur][16 + m16][kk];
            short8 a2 = *(const short8*)&h1[cur][32 + m16][kk];
            short8 a3 = *(const short8*)&h1[cur][48 + m16][kk];
            acc2[0] = __builtin_amdgcn_mfma_f32_16x16x32_bf16(a0, Breg[it], acc2[0], 0, 0, 0);
            acc2[1] = __builtin_amdgcn_mfma_f32_16x16x32_bf16(a1, Breg[it], acc2[1], 0, 0, 0);
            acc2[2] = __builtin_amdgcn_mfma_f32_16x16x32_bf16(a2, Breg[it], acc2[2], 0, 0, 0);
            acc2[3] = __builtin_amdgcn_mfma_f32_16x16x32_bf16(a3, Breg[it], acc2[3], 0, 0, 0);
        }
        if (hasNext) {
#pragma unroll
            for (int rr = 0; rr < 2; rr++) {
                int r = wave * 4 + 2 + rr;
                S8U hh;
#pragma unroll
                for (int e2 = 0; e2 < 4; e2++) {
                    float z0 = (e2 < 2) ? zA[e2 * 2] : zB[e2 * 2 - 4];
                    float z1 = (e2 < 2) ? zA[e2 * 2 + 1] : zB[e2 * 2 - 3];
                    float f0 = fmaxf(z0 + bf2f((ushort)uu[rr][e2 * 2]) + bf2f((ushort)vv[rr][e2 * 2]), 0.f);
                    float f1 = fmaxf(z1 + bf2f((ushort)uu[rr][e2 * 2 + 1]) + bf2f((ushort)vv[rr][e2 * 2 + 1]), 0.f);
                    hh.u[e2] = pk_bf16(f0, f1);
                }
                *(short8*)&h1[nxt][r][c8] = hh.s;
            }
        }

        // epilogue: fused relu + partial dot (16 cols) via shfl-reduce over m16
#pragma unroll
        for (int mt = 0; mt < 4; mt++)
#pragma unroll
            for (int tt = 0; tt < 4; tt++) {
                float s = fmaxf(acc2[mt][tt] + eb2v, 0.f) * ew3v;
                s += __shfl_xor(s, 1);
                s += __shfl_xor(s, 2);
                s += __shfl_xor(s, 4);
                s += __shfl_xor(s, 8);
                if (m16 == 0) part[mt * 16 + quad * 4 + tt][wave] = s;
            }
        __syncthreads();

        if (tid < MTILE) {
            int p = (ti0 + t) * MTILE + tid;
            if (p < NPAIRS) {
                float v = eb3[0];
#pragma unroll
                for (int w = 0; w < 16; w++) v += part[tid][w];
                out_edges[b * NPAIRS + p] = sigmoidf(v);
            }
        }
        __syncthreads();
    }
}

extern "C" void kernel_launch(void* const* d_in, const int* in_sizes, int n_in,
                              void* d_out, int out_size, void* d_ws, size_t ws_size,
                              hipStream_t stream) {
    const float* z   = (const float*)d_in[0];
    const float* nw1 = (const float*)d_in[1];
    const float* nb1 = (const float*)d_in[2];
    const float* nw2 = (const float*)d_in[3];
    const float* nb2 = (const float*)d_in[4];
    const float* nw3 = (const float*)d_in[5];
    const float* nb3 = (const float*)d_in[6];
    const float* ew1 = (const float*)d_in[7];
    const float* eb1 = (const float*)d_in[8];
    const float* ew2 = (const float*)d_in[9];
    const float* eb2 = (const float*)d_in[10];
    const float* ew3 = (const float*)d_in[11];
    const float* eb3 = (const float*)d_in[12];

    char* ws = (char*)d_ws;
    int*    ptab = (int*)(ws);                       // 1225*4
    ushort* h2b  = (ushort*)(ws + 262144);           // 131072
    ushort* nf   = (ushort*)(ws + 393216);           // 1638400
    ushort* ew2T = (ushort*)(ws + 2031616);          // 262144
    ushort* wijT = (ushort*)(ws + 2293760);          // 262144
    ushort* nw3T = (ushort*)(ws + 2555904);          // 6553600
    float*  Zc   = (float*)(ws + 9109504);           // 262144
    ushort* UV   = (ushort*)(ws + 9371648);          // 13107200

    float* out_nodes = (float*)d_out;                // 128*6400
    float* out_edges = out_nodes + BATCH * NODE_OUT; // 128*1225

    k_prep_all<<<PREPK_NB, 256, 0, stream>>>(nw3, nw3T, ew1, ew2, ew2T, wijT,
                                             z, eb1, Zc, nw1, nb1, nw2, nb2,
                                             h2b, ptab);
    k_node_out_mfma<<<200, 256, 0, stream>>>(h2b, nw3T, nb3, out_nodes, nf);
    k_uv<<<400, 256, 0, stream>>>(nf, wijT, UV);
    k_edge9<<<NBLK, 1024, 0, stream>>>(Zc, UV, ew2T, ew3, eb2, eb3, ptab, out_edges);
}